// Round 4
// baseline (196.365 us; speedup 1.0000x reference)
//
#include <hip/hip_runtime.h>
#include <hip/hip_bf16.h>

#define S_LEN 2048
#define D_DIM 1024
#define NHEAD 16
#define HDIM  64
#define BATCH 4
#define MROWS (BATCH*S_LEN)   /* 8192 */
#define QKV_LD 3072

typedef short bf16x8 __attribute__((ext_vector_type(8)));
typedef float f32x4  __attribute__((ext_vector_type(4)));
typedef float f32x16 __attribute__((ext_vector_type(16)));
typedef unsigned short u16;

#if __has_builtin(__builtin_amdgcn_exp2f)
#define EXP2(x) __builtin_amdgcn_exp2f(x)
#else
#define EXP2(x) __expf((x) * 0.6931471805599453f)
#endif

__device__ inline u16 f2bf(float f) {
  union { float f; unsigned u; } v; v.f = f;
  unsigned r = v.u + 0x7fff + ((v.u >> 16) & 1);   // RNE
  return (u16)(r >> 16);
}

__device__ inline unsigned cvtpk(float lo, float hi_) {
  unsigned d;
  asm("v_cvt_pk_bf16_f32 %0, %1, %2" : "=v"(d) : "v"(lo), "v"(hi_));
  return d;
}

__device__ inline void perm32swap(unsigned& a, unsigned& b) {
  asm volatile("v_permlane32_swap_b32 %0, %1" : "+v"(a), "+v"(b));
}

__device__ inline void gload_lds16(const void* g, void* l) {
  __builtin_amdgcn_global_load_lds(
      (const __attribute__((address_space(1))) void*)g,
      (__attribute__((address_space(3))) void*)l, 16, 0, 0);
}

// ---------------- fp32 -> bf16 convert (vectorized) ----------------
__global__ void cvt_x_kernel(const float* __restrict__ x, u16* __restrict__ xb, int n4) {
  int i = blockIdx.x * 256 + threadIdx.x;
  if (i >= n4) return;
  float4 v = reinterpret_cast<const float4*>(x)[i];
  ushort4 o;
  o.x = f2bf(v.x); o.y = f2bf(v.y); o.z = f2bf(v.z); o.w = f2bf(v.w);
  reinterpret_cast<ushort4*>(xb)[i] = o;
}

// ---------------- weight transpose: W[K][N] fp32 -> Wt[N][K] bf16 ----------------
__global__ void transpose_w_kernel(const float* __restrict__ w, u16* __restrict__ wt) {
  __shared__ float t[32][33];
  int tx = threadIdx.x, ty = threadIdx.y;
  int n0 = blockIdx.x * 32, k0 = blockIdx.y * 32;
#pragma unroll
  for (int j = 0; j < 32; j += 8)
    t[ty + j][tx] = w[(size_t)(k0 + ty + j) * D_DIM + n0 + tx];
  __syncthreads();
#pragma unroll
  for (int j = 0; j < 32; j += 8)
    wt[(size_t)(n0 + ty + j) * D_DIM + k0 + tx] = f2bf(t[tx][ty + j]);
}

// ---------------- K fragment-pack ----------------
__global__ __launch_bounds__(256) void pack_k_kernel(const u16* __restrict__ QKV,
                                                     u16* __restrict__ KP) {
  int tid = threadIdx.x;
  int j = blockIdx.x, bh = blockIdx.y;
  int s = tid >> 6, lane = tid & 63;
  int lq = lane & 31, hi = lane >> 5;
  int b = bh >> 4, h = bh & 15;
  const u16* src = QKV + (size_t)(b * S_LEN + j * 32 + lq) * QKV_LD
                   + 1024 + h * HDIM + s * 16 + hi * 8;
  bf16x8 v = *(const bf16x8*)src;
  *(bf16x8*)(KP + ((size_t)(bh * 64 + j) * 4 + s) * 512 + lane * 8) = v;
}

// ---------------- V fragment-pack (transposed) ----------------
__global__ __launch_bounds__(256) void pack_v_kernel(const u16* __restrict__ QKV,
                                                     u16* __restrict__ VP) {
  int tid = threadIdx.x;
  int j = blockIdx.x, bh = blockIdx.y;
  int c = tid >> 6, lane = tid & 63;
  int lq = lane & 31, hi = lane >> 5;
  int b = bh >> 4, h = bh & 15;
  int d = (c >> 1) * 32 + lq;
  int s0 = j * 32 + (c & 1) * 16 + hi * 8;
  const u16* src = QKV + (size_t)(b * S_LEN + s0) * QKV_LD + 2048 + h * HDIM + d;
  u16 tmp[8];
#pragma unroll
  for (int e = 0; e < 8; ++e) tmp[e] = src[(size_t)e * QKV_LD];
  *(bf16x8*)(VP + ((size_t)(bh * 64 + j) * 4 + c) * 512 + lane * 8) = *(bf16x8*)tmp;
}

// ================= 256x256 8-phase GEMM (T2+T3+T4+T5), K=1024 =================
// C[M][ldc] = A[M][1024] * Bt[N][1024]^T. 512 thr (8 waves 2Mx4N), BK=64,
// 128KB LDS double-buffered; counted vmcnt(4) at phases 4/8 only.
#define BAR() asm volatile("s_barrier" ::: "memory")
#define WAITV(N) asm volatile("s_waitcnt vmcnt(" #N ")" ::: "memory")
#define PRIO1() __builtin_amdgcn_s_setprio(1)
#define PRIO0() __builtin_amdgcn_s_setprio(0)

// staging: linear LDS dest, inverse-swizzled global source (chunk o <- o^(r&7))
#define STAGE(bufv, ab, h, gptr) {                                              \
  const u16* _s = (gptr) + (size_t)(wid * 8 + (lane >> 3)) * 1024               \
                  + (size_t)((((lane & 7) ^ (lane >> 3)) * 8));                 \
  gload_lds16(_s,              &lds[bufv][ab][(h) * 8192 + wid * 512]);         \
  gload_lds16(_s + 64 * 1024,  &lds[bufv][ab][(h) * 8192 + 4096 + wid * 512]); }

// swizzled fragment read: byte = r*128 + (c2 ^ ((r&7)<<4));  r&7 == fr&7
#define RDF(bufv, ab, r_, c2_) \
  (*(const bf16x8*)((const char*)&lds[bufv][ab][0] + ((r_) * 128 + ((c2_) ^ rxA))))

#define READ_ALO(bufv) { _Pragma("unroll") for (int mt = 0; mt < 4; mt++)       \
  _Pragma("unroll") for (int ks = 0; ks < 2; ks++)                              \
    fa[mt][ks] = RDF(bufv, 0, wm + mt * 16 + fr, ks * 64 + fq * 16); }
#define READ_AHI(bufv) { _Pragma("unroll") for (int mt = 0; mt < 4; mt++)       \
  _Pragma("unroll") for (int ks = 0; ks < 2; ks++)                              \
    fa[4 + mt][ks] = RDF(bufv, 0, wm + 64 + mt * 16 + fr, ks * 64 + fq * 16); }
#define READ_BLO(bufv) { _Pragma("unroll") for (int nt = 0; nt < 2; nt++)       \
  _Pragma("unroll") for (int ks = 0; ks < 2; ks++)                              \
    fb[nt][ks] = RDF(bufv, 1, wn + nt * 16 + fr, ks * 64 + fq * 16); }
#define READ_BHI(bufv) { _Pragma("unroll") for (int nt = 0; nt < 2; nt++)       \
  _Pragma("unroll") for (int ks = 0; ks < 2; ks++)                              \
    fb[2 + nt][ks] = RDF(bufv, 1, wn + 32 + nt * 16 + fr, ks * 64 + fq * 16); }

#define QUAD(mh, nh) { PRIO1();                                                 \
  _Pragma("unroll") for (int mt = 0; mt < 4; mt++)                              \
  _Pragma("unroll") for (int nt = 0; nt < 2; nt++)                              \
  _Pragma("unroll") for (int ks = 0; ks < 2; ks++)                              \
    acc[(mh) * 4 + mt][(nh) * 2 + nt] = __builtin_amdgcn_mfma_f32_16x16x32_bf16(\
        fa[(mh) * 4 + mt][ks], fb[(nh) * 2 + nt][ks],                           \
        acc[(mh) * 4 + mt][(nh) * 2 + nt], 0, 0, 0);                            \
  PRIO0(); }

#define APTR(h, kt) (A  + (size_t)(bm * 256 + (h) * 128) * 1024 + (size_t)(kt) * 64)
#define BPTR(h, kt) (Bt + (size_t)(bn * 256 + (h) * 128) * 1024 + (size_t)(kt) * 64)

template <int EPI>  // 0: bf16 C, 1: fp32 C + bias
__global__ __launch_bounds__(512, 2) void gemm8p_kernel(
    const u16* __restrict__ A, const u16* __restrict__ Bt,
    void* __restrict__ Cv, const float* __restrict__ bias, int nbx, int ldc) {
  __shared__ u16 lds[2][2][16384];   // [buf][A/B][256*64]
  const int tid = threadIdx.x, wid = tid >> 6, lane = tid & 63;
  const int fr = lane & 15, fq = lane >> 4;
  const int wm = (wid >> 2) * 128, wn = (wid & 3) * 64;
  const int rxA = (fr & 7) << 4;
  const int nwg = gridDim.x, cpx = nwg >> 3, wg = blockIdx.x;
  const int swz = (wg & 7) * cpx + (wg >> 3);     // XCD swizzle (nwg % 8 == 0)
  const int bm = swz / nbx, bn = swz % nbx;

  bf16x8 fa[8][2], fb[4][2];
  f32x4 acc[8][4] = {};

  // prologue: tile0 -> buf0 (all 4 halves), tile1 -> buf1 (A halves)
  STAGE(0, 0, 0, APTR(0, 0)); STAGE(0, 0, 1, APTR(1, 0));
  STAGE(0, 1, 0, BPTR(0, 0)); STAGE(0, 1, 1, BPTR(1, 0));
  STAGE(1, 0, 0, APTR(0, 1)); STAGE(1, 0, 1, APTR(1, 1));
  WAITV(4);
  BAR();

  for (int i = 0; i < 8; i++) {
    const int t = 2 * i;
    const int t2 = (t + 2 < 16) ? t + 2 : 0;
    const int t3 = (t + 3 < 16) ? t + 3 : 0;
    // ---- tile t in buf0 ----
    READ_ALO(0); READ_BLO(0);
    STAGE(1, 1, 0, BPTR(0, t + 1));
    BAR(); QUAD(0, 0); BAR();                     // P1: (Mlo,Nlo)

    READ_AHI(0);
    STAGE(1, 1, 1, BPTR(1, t + 1));
    BAR(); QUAD(1, 0); BAR();                     // P2: (Mhi,Nlo)

    READ_BHI(0);
    STAGE(0, 0, 0, APTR(0, t2));
    BAR(); QUAD(0, 1); BAR();                     // P3: (Mlo,Nhi)

    STAGE(0, 0, 1, APTR(1, t2));
    WAITV(4);
    BAR(); QUAD(1, 1); BAR();                     // P4: (Mhi,Nhi)
    // ---- tile t+1 in buf1 ----
    READ_ALO(1); READ_BLO(1);
    STAGE(0, 1, 0, BPTR(0, t2));
    BAR(); QUAD(0, 0); BAR();                     // P5

    READ_AHI(1);
    STAGE(0, 1, 1, BPTR(1, t2));
    BAR(); QUAD(1, 0); BAR();                     // P6

    READ_BHI(1);
    STAGE(1, 0, 0, APTR(0, t3));
    BAR(); QUAD(0, 1); BAR();                     // P7

    STAGE(1, 0, 1, APTR(1, t3));
    WAITV(4);
    BAR(); QUAD(1, 1); BAR();                     // P8
  }
  WAITV(0);

#pragma unroll
  for (int mt = 0; mt < 8; mt++)
#pragma unroll
    for (int nt = 0; nt < 4; nt++)
#pragma unroll
      for (int j = 0; j < 4; j++) {
        int row = bm * 256 + wm + mt * 16 + fq * 4 + j;
        int col = bn * 256 + wn + nt * 16 + fr;
        if (EPI == 0) {
          ((u16*)Cv)[(size_t)row * ldc + col] = f2bf(acc[mt][nt][j]);
        } else {
          ((float*)Cv)[(size_t)row * ldc + col] = acc[mt][nt][j] + bias[col];
        }
      }
}

// ---------------- flash attention (causal), swapped-operand 32x32 MFMA ----------------
__global__ __launch_bounds__(256) void attn_kernel(
    const u16* __restrict__ QKV, const u16* __restrict__ KP,
    const u16* __restrict__ VP, u16* __restrict__ O) {
  const int tid = threadIdx.x, wid = tid >> 6, lane = tid & 63;
  const int lq = lane & 31, hi = lane >> 5;
  int f = blockIdx.x;
  int xcd = f & 7, kk = f >> 3;
  int bh = xcd * 8 + (kk & 7);
  int qblk = 15 - (kk >> 3);
  int b = bh >> 4, h = bh & 15;
  int q0 = qblk * 128 + wid * 32;
  int q = q0 + lq;

  const u16* Qrow = QKV + (size_t)(b * S_LEN + q) * QKV_LD + h * HDIM;
  bf16x8 qf[4];
#pragma unroll
  for (int s = 0; s < 4; s++)
    qf[s] = *(const bf16x8*)(Qrow + s * 16 + hi * 8);

  const bf16x8* KPt = (const bf16x8*)KP + (size_t)bh * 64 * 4 * 64;
  const bf16x8* VPt = (const bf16x8*)VP + (size_t)bh * 64 * 4 * 64;

  f32x16 acc0 = {}, acc1 = {};
  float m = -3.0e38f, l = 0.f;
  const int nt = qblk * 4 + wid + 1;

  for (int t = 0; t < nt; ++t) {
    const int j0 = t * 32;
    const size_t fb = (size_t)t * 4 * 64 + lane;
    bf16x8 kf0 = KPt[fb], kf1 = KPt[fb + 64], kf2 = KPt[fb + 128], kf3 = KPt[fb + 192];
    bf16x8 vf00 = VPt[fb], vf01 = VPt[fb + 64], vf10 = VPt[fb + 128], vf11 = VPt[fb + 192];

    f32x16 sa = {};
    __builtin_amdgcn_s_setprio(1);
    sa = __builtin_amdgcn_mfma_f32_32x32x16_bf16(kf0, qf[0], sa, 0, 0, 0);
    sa = __builtin_amdgcn_mfma_f32_32x32x16_bf16(kf1, qf[1], sa, 0, 0, 0);
    sa = __builtin_amdgcn_mfma_f32_32x32x16_bf16(kf2, qf[2], sa, 0, 0, 0);
    sa = __builtin_amdgcn_mfma_f32_32x32x16_bf16(kf3, qf[3], sa, 0, 0, 0);
    __builtin_amdgcn_s_setprio(0);

    float p[16];
#pragma unroll
    for (int r = 0; r < 16; ++r) p[r] = sa[r] * 0.1803368801f;

    if (t == nt - 1) {
#pragma unroll
      for (int r = 0; r < 16; ++r) {
        int kidx = j0 + (r & 3) + 8 * (r >> 2) + 4 * hi;
        if (kidx > q) p[r] = -3.0e38f;
      }
    }

    float x8[8], x4[4], x2[2];
#pragma unroll
    for (int i = 0; i < 8; ++i) x8[i] = fmaxf(p[2 * i], p[2 * i + 1]);
#pragma unroll
    for (int i = 0; i < 4; ++i) x4[i] = fmaxf(x8[2 * i], x8[2 * i + 1]);
    x2[0] = fmaxf(x4[0], x4[1]); x2[1] = fmaxf(x4[2], x4[3]);
    float pm = fmaxf(x2[0], x2[1]);
    pm = fmaxf(pm, __shfl_xor(pm, 32));

    if (__any(pm > m + 11.5f)) {
      float mn = fmaxf(m, pm);
      float sc = EXP2(m - mn);
      l *= sc;
#pragma unroll
      for (int r = 0; r < 16; ++r) { acc0[r] *= sc; acc1[r] *= sc; }
      m = mn;
    }

    float rs = 0.f;
#pragma unroll
    for (int r = 0; r < 16; ++r) { p[r] = EXP2(p[r] - m); rs += p[r]; }
    rs += __shfl_xor(rs, 32);
    l += rs;

    unsigned c0 = cvtpk(p[0],  p[1]),  c1 = cvtpk(p[2],  p[3]);
    unsigned c2 = cvtpk(p[4],  p[5]),  c3 = cvtpk(p[6],  p[7]);
    unsigned c4 = cvtpk(p[8],  p[9]),  c5 = cvtpk(p[10], p[11]);
    unsigned c6 = cvtpk(p[12], p[13]), c7 = cvtpk(p[14], p[15]);
    perm32swap(c0, c2); perm32swap(c1, c3);
    perm32swap(c4, c6); perm32swap(c5, c7);
    union U4 { unsigned u[4]; bf16x8 v; } F0, F1;
    F0.u[0] = c0; F0.u[1] = c1; F0.u[2] = c2; F0.u[3] = c3;
    F1.u[0] = c4; F1.u[1] = c5; F1.u[2] = c6; F1.u[3] = c7;

    __builtin_amdgcn_s_setprio(1);
    acc0 = __builtin_amdgcn_mfma_f32_32x32x16_bf16(vf00, F0.v, acc0, 0, 0, 0);
    acc0 = __builtin_amdgcn_mfma_f32_32x32x16_bf16(vf01, F1.v, acc0, 0, 0, 0);
    acc1 = __builtin_amdgcn_mfma_f32_32x32x16_bf16(vf10, F0.v, acc1, 0, 0, 0);
    acc1 = __builtin_amdgcn_mfma_f32_32x32x16_bf16(vf11, F1.v, acc1, 0, 0, 0);
    __builtin_amdgcn_s_setprio(0);
  }

  float inv = 1.f / l;
  u16* Orow = O + (size_t)(b * S_LEN + q) * D_DIM + h * HDIM;
#pragma unroll
  for (int g = 0; g < 4; ++g) {
    ushort4 o4;
    o4.x = f2bf(acc0[g * 4 + 0] * inv);
    o4.y = f2bf(acc0[g * 4 + 1] * inv);
    o4.z = f2bf(acc0[g * 4 + 2] * inv);
    o4.w = f2bf(acc0[g * 4 + 3] * inv);
    *(ushort4*)(Orow + 8 * g + 4 * hi) = o4;
  }
#pragma unroll
  for (int g = 0; g < 4; ++g) {
    ushort4 o4;
    o4.x = f2bf(acc1[g * 4 + 0] * inv);
    o4.y = f2bf(acc1[g * 4 + 1] * inv);
    o4.z = f2bf(acc1[g * 4 + 2] * inv);
    o4.w = f2bf(acc1[g * 4 + 3] * inv);
    *(ushort4*)(Orow + 32 + 8 * g + 4 * hi) = o4;
  }
}

// ---------------- launcher ----------------
extern "C" void kernel_launch(void* const* d_in, const int* in_sizes, int n_in,
                              void* d_out, int out_size, void* d_ws, size_t ws_size,
                              hipStream_t stream) {
  const float* x  = (const float*)d_in[0];
  const float* wq = (const float*)d_in[1];
  const float* wk = (const float*)d_in[2];
  const float* wv = (const float*)d_in[3];
  const float* wo = (const float*)d_in[4];
  const float* ob = (const float*)d_in[5];
  float* out = (float*)d_out;

  char* ws = (char*)d_ws;
  u16* Xb    = (u16*)(ws);                              // slot A: Xb then Ab
  u16* Ab    = (u16*)(ws);
  u16* QKV   = (u16*)(ws + (size_t)16 * 1024 * 1024);   // 48 MB
  u16* KPb   = (u16*)(ws + (size_t)64 * 1024 * 1024);   // 16 MB
  u16* VPb   = (u16*)(ws + (size_t)80 * 1024 * 1024);   // 16 MB
  u16* WqkvT = (u16*)(ws + (size_t)96 * 1024 * 1024);   // 6 MB
  u16* WoT   = (u16*)(ws + (size_t)102 * 1024 * 1024);  // 2 MB

  cvt_x_kernel<<<(MROWS * D_DIM / 4) / 256, 256, 0, stream>>>(x, Xb, MROWS * D_DIM / 4);

  dim3 tb(32, 8);
  transpose_w_kernel<<<dim3(32, 32), tb, 0, stream>>>(wq, WqkvT);
  transpose_w_kernel<<<dim3(32, 32), tb, 0, stream>>>(wk, WqkvT + 1024 * 1024);
  transpose_w_kernel<<<dim3(32, 32), tb, 0, stream>>>(wv, WqkvT + 2 * 1024 * 1024);
  transpose_w_kernel<<<dim3(32, 32), tb, 0, stream>>>(wo, WoT);

  // fused QKV projection: [8192,1024] x [1024,3072]
  gemm8p_kernel<0><<<dim3((MROWS / 256) * (QKV_LD / 256)), 512, 0, stream>>>(
      Xb, WqkvT, QKV, nullptr, QKV_LD / 256, QKV_LD);

  pack_k_kernel<<<dim3(64, 64), 256, 0, stream>>>(QKV, KPb);
  pack_v_kernel<<<dim3(64, 64), 256, 0, stream>>>(QKV, VPb);

  attn_kernel<<<dim3(1024), 256, 0, stream>>>(QKV, KPb, VPb, Ab);

  gemm8p_kernel<1><<<dim3((MROWS / 256) * (D_DIM / 256)), 512, 0, stream>>>(
      Ab, WoT, out, ob, D_DIM / 256, D_DIM);
}

// Round 5
// 191.734 us; speedup vs baseline: 1.0242x; 1.0242x over previous
//
#include <hip/hip_runtime.h>
#include <hip/hip_bf16.h>

#define S_LEN 2048
#define D_DIM 1024
#define NHEAD 16
#define HDIM  64
#define BATCH 4
#define MROWS (BATCH*S_LEN)   /* 8192 */
#define QKV_LD 3072

typedef short bf16x8 __attribute__((ext_vector_type(8)));
typedef float f32x4  __attribute__((ext_vector_type(4)));
typedef float f32x16 __attribute__((ext_vector_type(16)));
typedef unsigned short u16;

#if __has_builtin(__builtin_amdgcn_exp2f)
#define EXP2(x) __builtin_amdgcn_exp2f(x)
#else
#define EXP2(x) __expf((x) * 0.6931471805599453f)
#endif

__device__ inline u16 f2bf(float f) {
  union { float f; unsigned u; } v; v.f = f;
  unsigned r = v.u + 0x7fff + ((v.u >> 16) & 1);   // RNE
  return (u16)(r >> 16);
}

__device__ inline unsigned cvtpk(float lo, float hi_) {
  unsigned d;
  asm("v_cvt_pk_bf16_f32 %0, %1, %2" : "=v"(d) : "v"(lo), "v"(hi_));
  return d;
}

__device__ inline void perm32swap(unsigned& a, unsigned& b) {
  asm volatile("v_permlane32_swap_b32 %0, %1" : "+v"(a), "+v"(b));
}

__device__ inline void gload_lds16(const void* g, void* l) {
  __builtin_amdgcn_global_load_lds(
      (const __attribute__((address_space(1))) void*)g,
      (__attribute__((address_space(3))) void*)l, 16, 0, 0);
}

// ---------------- fp32 -> bf16 convert (vectorized) ----------------
__global__ void cvt_x_kernel(const float* __restrict__ x, u16* __restrict__ xb, int n4) {
  int i = blockIdx.x * 256 + threadIdx.x;
  if (i >= n4) return;
  float4 v = reinterpret_cast<const float4*>(x)[i];
  ushort4 o;
  o.x = f2bf(v.x); o.y = f2bf(v.y); o.z = f2bf(v.z); o.w = f2bf(v.w);
  reinterpret_cast<ushort4*>(xb)[i] = o;
}

// ---------------- weight transpose: W[K][N] fp32 -> Wt[N][K] bf16 ----------------
__global__ void transpose_w_kernel(const float* __restrict__ w, u16* __restrict__ wt) {
  __shared__ float t[32][33];
  int tx = threadIdx.x, ty = threadIdx.y;
  int n0 = blockIdx.x * 32, k0 = blockIdx.y * 32;
#pragma unroll
  for (int j = 0; j < 32; j += 8)
    t[ty + j][tx] = w[(size_t)(k0 + ty + j) * D_DIM + n0 + tx];
  __syncthreads();
#pragma unroll
  for (int j = 0; j < 32; j += 8)
    wt[(size_t)(n0 + ty + j) * D_DIM + k0 + tx] = f2bf(t[tx][ty + j]);
}

// ---------------- K fragment-pack ----------------
__global__ __launch_bounds__(256) void pack_k_kernel(const u16* __restrict__ QKV,
                                                     u16* __restrict__ KP) {
  int tid = threadIdx.x;
  int j = blockIdx.x, bh = blockIdx.y;
  int s = tid >> 6, lane = tid & 63;
  int lq = lane & 31, hi = lane >> 5;
  int b = bh >> 4, h = bh & 15;
  const u16* src = QKV + (size_t)(b * S_LEN + j * 32 + lq) * QKV_LD
                   + 1024 + h * HDIM + s * 16 + hi * 8;
  bf16x8 v = *(const bf16x8*)src;
  *(bf16x8*)(KP + ((size_t)(bh * 64 + j) * 4 + s) * 512 + lane * 8) = v;
}

// ---------------- V fragment-pack (transposed) ----------------
__global__ __launch_bounds__(256) void pack_v_kernel(const u16* __restrict__ QKV,
                                                     u16* __restrict__ VP) {
  int tid = threadIdx.x;
  int j = blockIdx.x, bh = blockIdx.y;
  int c = tid >> 6, lane = tid & 63;
  int lq = lane & 31, hi = lane >> 5;
  int b = bh >> 4, h = bh & 15;
  int d = (c >> 1) * 32 + lq;
  int s0 = j * 32 + (c & 1) * 16 + hi * 8;
  const u16* src = QKV + (size_t)(b * S_LEN + s0) * QKV_LD + 2048 + h * HDIM + d;
  u16 tmp[8];
#pragma unroll
  for (int e = 0; e < 8; ++e) tmp[e] = src[(size_t)e * QKV_LD];
  *(bf16x8*)(VP + ((size_t)(bh * 64 + j) * 4 + c) * 512 + lane * 8) = *(bf16x8*)tmp;
}

// ================= 256x128 8-phase GEMM (T2+T3+T4+T5), K=1024 =================
// C[M][ldc] = A[M][1024] * Bt[N][1024]^T. 512 thr (8 waves 4Mx2N, 64x64 wave tile),
// BK=64, 96KB LDS dbuf. Grids are exact multiples of 256 CUs (no tail).
#define BAR() asm volatile("s_barrier" ::: "memory")
#define WAITV(N) asm volatile("s_waitcnt vmcnt(" #N ")" ::: "memory")
#define PRIO1() __builtin_amdgcn_s_setprio(1)
#define PRIO0() __builtin_amdgcn_s_setprio(0)

// stage unit: 64 rows x 64 cols bf16 (8KB), 1 gload_lds16/thread.
// linear LDS dest; inverse-swizzled global source chunk (rule #21).
#define STAGE_U(ldsArr, u, gptr) {                                              \
  const u16* _s = (gptr) + (size_t)((u) * 64 + (tid >> 3)) * 1024               \
                  + (size_t)(((tid & 7) ^ ((tid >> 3) & 7)) * 8);               \
  gload_lds16(_s, &ldsArr[((u) * 64 + wid * 8) * 64]); }

// swizzled fragment read: byte = r*128 + (c2 ^ ((r&7)<<4))
#define RDF(ldsArr, r_, c2_) \
  (*(const bf16x8*)((const char*)&ldsArr[0] + ((r_) * 128 + ((c2_) ^ rxA))))

#define READ_A_LO(buf) { _Pragma("unroll") for (int mt = 0; mt < 2; mt++)       \
  _Pragma("unroll") for (int ks = 0; ks < 2; ks++)                              \
    fa[mt][ks] = RDF(lA[buf], wm + mt * 16 + fr, ks * 64 + fq * 16); }
#define READ_A_HI(buf) { _Pragma("unroll") for (int mt = 0; mt < 2; mt++)       \
  _Pragma("unroll") for (int ks = 0; ks < 2; ks++)                              \
    fa[2 + mt][ks] = RDF(lA[buf], wm + 32 + mt * 16 + fr, ks * 64 + fq * 16); }
#define READ_B_LO(buf) { _Pragma("unroll") for (int nt = 0; nt < 2; nt++)       \
  _Pragma("unroll") for (int ks = 0; ks < 2; ks++)                              \
    fb[nt][ks] = RDF(lB[buf], wn + nt * 16 + fr, ks * 64 + fq * 16); }
#define READ_B_HI(buf) { _Pragma("unroll") for (int nt = 0; nt < 2; nt++)       \
  _Pragma("unroll") for (int ks = 0; ks < 2; ks++)                              \
    fb[2 + nt][ks] = RDF(lB[buf], wn + 32 + nt * 16 + fr, ks * 64 + fq * 16); }

#define QUAD(mh, nh) { PRIO1();                                                 \
  _Pragma("unroll") for (int mt = 0; mt < 2; mt++)                              \
  _Pragma("unroll") for (int nt = 0; nt < 2; nt++)                              \
  _Pragma("unroll") for (int ks = 0; ks < 2; ks++)                              \
    acc[(mh) * 2 + mt][(nh) * 2 + nt] = __builtin_amdgcn_mfma_f32_16x16x32_bf16(\
        fa[(mh) * 2 + mt][ks], fb[(nh) * 2 + nt][ks],                           \
        acc[(mh) * 2 + mt][(nh) * 2 + nt], 0, 0, 0);                            \
  PRIO0(); }

#define APTR(kt) (A  + (size_t)(bm * 256) * 1024 + (size_t)(kt) * 64)
#define BPTR(kt) (Bt + (size_t)(bn * 128) * 1024 + (size_t)(kt) * 64)

template <int EPI>  // 0: bf16 C, 1: fp32 C + bias
__global__ __launch_bounds__(512) void gemm8p_kernel(
    const u16* __restrict__ A, const u16* __restrict__ Bt,
    void* __restrict__ Cv, const float* __restrict__ bias, int nbx, int ldc) {
  __shared__ u16 lA[2][16384];   // 256x64 per buf
  __shared__ u16 lB[2][8192];    // 128x64 per buf
  const int tid = threadIdx.x, wid = tid >> 6, lane = tid & 63;
  const int fr = lane & 15, fq = lane >> 4;
  const int wm = (wid >> 1) * 64, wn = (wid & 1) * 64;
  const int rxA = (fr & 7) << 4;
  const int nwg = gridDim.x, cpx = nwg >> 3, wg = blockIdx.x;
  const int swz = (wg & 7) * cpx + (wg >> 3);     // XCD swizzle (nwg % 8 == 0)
  const int bm = swz / nbx, bn = swz % nbx;

  bf16x8 fa[4][2], fb[4][2];
  f32x4 acc[4][4] = {};

  // prologue: tile0 A+B -> buf0, tile1 A -> buf1  (10 loads)
  STAGE_U(lA[0], 0, APTR(0)); STAGE_U(lA[0], 1, APTR(0));
  STAGE_U(lA[0], 2, APTR(0)); STAGE_U(lA[0], 3, APTR(0));
  STAGE_U(lB[0], 0, BPTR(0)); STAGE_U(lB[0], 1, BPTR(0));
  STAGE_U(lA[1], 0, APTR(1)); STAGE_U(lA[1], 1, APTR(1));
  STAGE_U(lA[1], 2, APTR(1)); STAGE_U(lA[1], 3, APTR(1));
  WAITV(4);
  BAR();

  for (int i = 0; i < 8; i++) {
    const int t = 2 * i;
    const int t2 = (t + 2 < 16) ? t + 2 : 0;
    const int t3 = (t + 3 < 16) ? t + 3 : 0;
    // ---- tile t in buf0 ----
    READ_A_LO(0); READ_B_LO(0);
    STAGE_U(lB[1], 0, BPTR(t + 1));
    BAR(); QUAD(0, 0); BAR();                     // P1

    READ_A_HI(0);
    STAGE_U(lB[1], 1, BPTR(t + 1));
    BAR(); QUAD(1, 0); BAR();                     // P2

    READ_B_HI(0);
    STAGE_U(lA[0], 0, APTR(t2)); STAGE_U(lA[0], 1, APTR(t2));
    BAR(); QUAD(0, 1); BAR();                     // P3

    STAGE_U(lA[0], 2, APTR(t2)); STAGE_U(lA[0], 3, APTR(t2));
    WAITV(4);
    BAR(); QUAD(1, 1); BAR();                     // P4
    // ---- tile t+1 in buf1 ----
    READ_A_LO(1); READ_B_LO(1);
    STAGE_U(lB[0], 0, BPTR(t2));
    BAR(); QUAD(0, 0); BAR();                     // P5

    READ_A_HI(1);
    STAGE_U(lB[0], 1, BPTR(t2));
    BAR(); QUAD(1, 0); BAR();                     // P6

    READ_B_HI(1);
    STAGE_U(lA[1], 0, APTR(t3)); STAGE_U(lA[1], 1, APTR(t3));
    BAR(); QUAD(0, 1); BAR();                     // P7

    STAGE_U(lA[1], 2, APTR(t3)); STAGE_U(lA[1], 3, APTR(t3));
    WAITV(4);
    BAR(); QUAD(1, 1); BAR();                     // P8
  }
  WAITV(0);

#pragma unroll
  for (int mt = 0; mt < 4; mt++)
#pragma unroll
    for (int nt = 0; nt < 4; nt++)
#pragma unroll
      for (int j = 0; j < 4; j++) {
        int row = bm * 256 + wm + mt * 16 + fq * 4 + j;
        int col = bn * 128 + wn + nt * 16 + fr;
        if (EPI == 0) {
          ((u16*)Cv)[(size_t)row * ldc + col] = f2bf(acc[mt][nt][j]);
        } else {
          ((float*)Cv)[(size_t)row * ldc + col] = acc[mt][nt][j] + bias[col];
        }
      }
}

// ---------------- flash attention (causal), swapped-operand 32x32 MFMA ----------------
__global__ __launch_bounds__(256) void attn_kernel(
    const u16* __restrict__ QKV, const u16* __restrict__ KP,
    const u16* __restrict__ VP, u16* __restrict__ O) {
  const int tid = threadIdx.x, wid = tid >> 6, lane = tid & 63;
  const int lq = lane & 31, hi = lane >> 5;
  int f = blockIdx.x;
  int xcd = f & 7, kk = f >> 3;
  int bh = xcd * 8 + (kk & 7);
  int qblk = 15 - (kk >> 3);
  int b = bh >> 4, h = bh & 15;
  int q0 = qblk * 128 + wid * 32;
  int q = q0 + lq;

  const u16* Qrow = QKV + (size_t)(b * S_LEN + q) * QKV_LD + h * HDIM;
  bf16x8 qf[4];
#pragma unroll
  for (int s = 0; s < 4; s++)
    qf[s] = *(const bf16x8*)(Qrow + s * 16 + hi * 8);

  const bf16x8* KPt = (const bf16x8*)KP + (size_t)bh * 64 * 4 * 64;
  const bf16x8* VPt = (const bf16x8*)VP + (size_t)bh * 64 * 4 * 64;

  f32x16 acc0 = {}, acc1 = {};
  float m = -3.0e38f, l = 0.f;
  const int nt = qblk * 4 + wid + 1;

  for (int t = 0; t < nt; ++t) {
    const int j0 = t * 32;
    const size_t fb = (size_t)t * 4 * 64 + lane;
    bf16x8 kf0 = KPt[fb], kf1 = KPt[fb + 64], kf2 = KPt[fb + 128], kf3 = KPt[fb + 192];
    bf16x8 vf00 = VPt[fb], vf01 = VPt[fb + 64], vf10 = VPt[fb + 128], vf11 = VPt[fb + 192];

    f32x16 sa = {};
    __builtin_amdgcn_s_setprio(1);
    sa = __builtin_amdgcn_mfma_f32_32x32x16_bf16(kf0, qf[0], sa, 0, 0, 0);
    sa = __builtin_amdgcn_mfma_f32_32x32x16_bf16(kf1, qf[1], sa, 0, 0, 0);
    sa = __builtin_amdgcn_mfma_f32_32x32x16_bf16(kf2, qf[2], sa, 0, 0, 0);
    sa = __builtin_amdgcn_mfma_f32_32x32x16_bf16(kf3, qf[3], sa, 0, 0, 0);
    __builtin_amdgcn_s_setprio(0);

    float p[16];
#pragma unroll
    for (int r = 0; r < 16; ++r) p[r] = sa[r] * 0.1803368801f;

    if (t == nt - 1) {
#pragma unroll
      for (int r = 0; r < 16; ++r) {
        int kidx = j0 + (r & 3) + 8 * (r >> 2) + 4 * hi;
        if (kidx > q) p[r] = -3.0e38f;
      }
    }

    float x8[8], x4[4], x2[2];
#pragma unroll
    for (int i = 0; i < 8; ++i) x8[i] = fmaxf(p[2 * i], p[2 * i + 1]);
#pragma unroll
    for (int i = 0; i < 4; ++i) x4[i] = fmaxf(x8[2 * i], x8[2 * i + 1]);
    x2[0] = fmaxf(x4[0], x4[1]); x2[1] = fmaxf(x4[2], x4[3]);
    float pm = fmaxf(x2[0], x2[1]);
    pm = fmaxf(pm, __shfl_xor(pm, 32));

    if (__any(pm > m + 11.5f)) {
      float mn = fmaxf(m, pm);
      float sc = EXP2(m - mn);
      l *= sc;
#pragma unroll
      for (int r = 0; r < 16; ++r) { acc0[r] *= sc; acc1[r] *= sc; }
      m = mn;
    }

    float rs = 0.f;
#pragma unroll
    for (int r = 0; r < 16; ++r) { p[r] = EXP2(p[r] - m); rs += p[r]; }
    rs += __shfl_xor(rs, 32);
    l += rs;

    unsigned c0 = cvtpk(p[0],  p[1]),  c1 = cvtpk(p[2],  p[3]);
    unsigned c2 = cvtpk(p[4],  p[5]),  c3 = cvtpk(p[6],  p[7]);
    unsigned c4 = cvtpk(p[8],  p[9]),  c5 = cvtpk(p[10], p[11]);
    unsigned c6 = cvtpk(p[12], p[13]), c7 = cvtpk(p[14], p[15]);
    perm32swap(c0, c2); perm32swap(c1, c3);
    perm32swap(c4, c6); perm32swap(c5, c7);
    union U4 { unsigned u[4]; bf16x8 v; } F0, F1;
    F0.u[0] = c0; F0.u[1] = c1; F0.u[2] = c2; F0.u[3] = c3;
    F1.u[0] = c4; F1.u[1] = c5; F1.u[2] = c6; F1.u[3] = c7;

    __builtin_amdgcn_s_setprio(1);
    acc0 = __builtin_amdgcn_mfma_f32_32x32x16_bf16(vf00, F0.v, acc0, 0, 0, 0);
    acc0 = __builtin_amdgcn_mfma_f32_32x32x16_bf16(vf01, F1.v, acc0, 0, 0, 0);
    acc1 = __builtin_amdgcn_mfma_f32_32x32x16_bf16(vf10, F0.v, acc1, 0, 0, 0);
    acc1 = __builtin_amdgcn_mfma_f32_32x32x16_bf16(vf11, F1.v, acc1, 0, 0, 0);
    __builtin_amdgcn_s_setprio(0);
  }

  float inv = 1.f / l;
  u16* Orow = O + (size_t)(b * S_LEN + q) * D_DIM + h * HDIM;
#pragma unroll
  for (int g = 0; g < 4; ++g) {
    ushort4 o4;
    o4.x = f2bf(acc0[g * 4 + 0] * inv);
    o4.y = f2bf(acc0[g * 4 + 1] * inv);
    o4.z = f2bf(acc0[g * 4 + 2] * inv);
    o4.w = f2bf(acc0[g * 4 + 3] * inv);
    *(ushort4*)(Orow + 8 * g + 4 * hi) = o4;
  }
#pragma unroll
  for (int g = 0; g < 4; ++g) {
    ushort4 o4;
    o4.x = f2bf(acc1[g * 4 + 0] * inv);
    o4.y = f2bf(acc1[g * 4 + 1] * inv);
    o4.z = f2bf(acc1[g * 4 + 2] * inv);
    o4.w = f2bf(acc1[g * 4 + 3] * inv);
    *(ushort4*)(Orow + 32 + 8 * g + 4 * hi) = o4;
  }
}

// ---------------- launcher ----------------
extern "C" void kernel_launch(void* const* d_in, const int* in_sizes, int n_in,
                              void* d_out, int out_size, void* d_ws, size_t ws_size,
                              hipStream_t stream) {
  const float* x  = (const float*)d_in[0];
  const float* wq = (const float*)d_in[1];
  const float* wk = (const float*)d_in[2];
  const float* wv = (const float*)d_in[3];
  const float* wo = (const float*)d_in[4];
  const float* ob = (const float*)d_in[5];
  float* out = (float*)d_out;

  char* ws = (char*)d_ws;
  u16* Xb    = (u16*)(ws);                              // slot A: Xb then Ab
  u16* Ab    = (u16*)(ws);
  u16* QKV   = (u16*)(ws + (size_t)16 * 1024 * 1024);   // 48 MB
  u16* KPb   = (u16*)(ws + (size_t)64 * 1024 * 1024);   // 16 MB
  u16* VPb   = (u16*)(ws + (size_t)80 * 1024 * 1024);   // 16 MB
  u16* WqkvT = (u16*)(ws + (size_t)96 * 1024 * 1024);   // 6 MB
  u16* WoT   = (u16*)(ws + (size_t)102 * 1024 * 1024);  // 2 MB

  cvt_x_kernel<<<(MROWS * D_DIM / 4) / 256, 256, 0, stream>>>(x, Xb, MROWS * D_DIM / 4);

  dim3 tb(32, 8);
  transpose_w_kernel<<<dim3(32, 32), tb, 0, stream>>>(wq, WqkvT);
  transpose_w_kernel<<<dim3(32, 32), tb, 0, stream>>>(wk, WqkvT + 1024 * 1024);
  transpose_w_kernel<<<dim3(32, 32), tb, 0, stream>>>(wv, WqkvT + 2 * 1024 * 1024);
  transpose_w_kernel<<<dim3(32, 32), tb, 0, stream>>>(wo, WoT);

  // fused QKV projection: [8192,1024] x [1024,3072]; grid 768 = 3 exact rounds
  gemm8p_kernel<0><<<dim3((MROWS / 256) * (QKV_LD / 128)), 512, 0, stream>>>(
      Xb, WqkvT, QKV, nullptr, QKV_LD / 128, QKV_LD);

  pack_k_kernel<<<dim3(64, 64), 256, 0, stream>>>(QKV, KPb);
  pack_v_kernel<<<dim3(64, 64), 256, 0, stream>>>(QKV, VPb);

  attn_kernel<<<dim3(1024), 256, 0, stream>>>(QKV, KPb, VPb, Ab);

  // out projection: [8192,1024] x [1024,1024]; grid 256 = 1 exact round
  gemm8p_kernel<1><<<dim3((MROWS / 256) * (D_DIM / 128)), 512, 0, stream>>>(
      Ab, WoT, out, ob, D_DIM / 128, D_DIM);
}

// Round 6
// 177.583 us; speedup vs baseline: 1.1058x; 1.0797x over previous
//
#include <hip/hip_runtime.h>
#include <hip/hip_bf16.h>

#define S_LEN 2048
#define D_DIM 1024
#define NHEAD 16
#define HDIM  64
#define BATCH 4
#define MROWS (BATCH*S_LEN)   /* 8192 */

typedef short bf16x8 __attribute__((ext_vector_type(8)));
typedef float f32x4  __attribute__((ext_vector_type(4)));
typedef float f32x16 __attribute__((ext_vector_type(16)));
typedef unsigned short u16;

#if __has_builtin(__builtin_amdgcn_exp2f)
#define EXP2(x) __builtin_amdgcn_exp2f(x)
#else
#define EXP2(x) __expf((x) * 0.6931471805599453f)
#endif

__device__ inline u16 f2bf(float f) {
  union { float f; unsigned u; } v; v.f = f;
  unsigned r = v.u + 0x7fff + ((v.u >> 16) & 1);   // RNE
  return (u16)(r >> 16);
}

__device__ inline unsigned cvtpk(float lo, float hi_) {
  unsigned d;
  asm("v_cvt_pk_bf16_f32 %0, %1, %2" : "=v"(d) : "v"(lo), "v"(hi_));
  return d;
}

__device__ inline void perm32swap(unsigned& a, unsigned& b) {
  asm volatile("v_permlane32_swap_b32 %0, %1" : "+v"(a), "+v"(b));
}

__device__ inline void gload_lds16(const void* g, void* l) {
  __builtin_amdgcn_global_load_lds(
      (const __attribute__((address_space(1))) void*)g,
      (__attribute__((address_space(3))) void*)l, 16, 0, 0);
}

// ---------------- fp32 -> bf16 convert (vectorized) ----------------
__global__ void cvt_x_kernel(const float* __restrict__ x, u16* __restrict__ xb, int n4) {
  int i = blockIdx.x * 256 + threadIdx.x;
  if (i >= n4) return;
  float4 v = reinterpret_cast<const float4*>(x)[i];
  ushort4 o;
  o.x = f2bf(v.x); o.y = f2bf(v.y); o.z = f2bf(v.z); o.w = f2bf(v.w);
  reinterpret_cast<ushort4*>(xb)[i] = o;
}

// ---------------- all-weights transpose: W[K][N] fp32 -> Wt[N][K] bf16 ----------------
__global__ void transpose_w4_kernel(const float* __restrict__ wq, const float* __restrict__ wk,
                                    const float* __restrict__ wv, const float* __restrict__ wo,
                                    u16* __restrict__ wqkvT, u16* __restrict__ woT) {
  __shared__ float t[32][33];
  int z = blockIdx.z;
  const float* w = (z == 0) ? wq : (z == 1) ? wk : (z == 2) ? wv : wo;
  u16* wt = (z < 3) ? (wqkvT + (size_t)z * 1024 * 1024) : woT;
  int tx = threadIdx.x, ty = threadIdx.y;
  int n0 = blockIdx.x * 32, k0 = blockIdx.y * 32;
#pragma unroll
  for (int j = 0; j < 32; j += 8)
    t[ty + j][tx] = w[(size_t)(k0 + ty + j) * D_DIM + n0 + tx];
  __syncthreads();
#pragma unroll
  for (int j = 0; j < 32; j += 8)
    wt[(size_t)(n0 + ty + j) * D_DIM + k0 + tx] = f2bf(t[tx][ty + j]);
}

// ============ m97-structure 128x128 bf16 GEMM, fused epilogues ============
// EPI 0: QKV projection, N=3072. cols 0-1023 -> Qb row-major bf16;
//        cols 1024-2047 -> KP fragment-packed; cols 2048-3071 -> VP packed.
// EPI 1: out projection, N=1024, fp32 C + bias.
template <int EPI>
__global__ __launch_bounds__(256) void gemm_bt_kernel(
    const u16* __restrict__ A, const u16* __restrict__ Bt,
    void* __restrict__ Cv, u16* __restrict__ KP, u16* __restrict__ VP,
    const float* __restrict__ bias) {
  __shared__ u16 lA[128 * 32];
  __shared__ u16 lB[128 * 32];
  const int tid = threadIdx.x, wid = tid >> 6, lane = tid & 63;
  const int bm = blockIdx.y, bn = blockIdx.x;
  const int fr = lane & 15, fq = lane >> 4;
  const int r0 = wid * 32;
  const int srow = lane >> 2, scol = (lane & 3) * 8;
  const u16* gA = A + (size_t)(bm * 128 + r0 + srow) * 1024 + scol;
  const u16* gB = Bt + (size_t)(bn * 128 + r0 + srow) * 1024 + scol;
  u16* lA0 = &lA[r0 * 32];
  u16* lB0 = &lB[r0 * 32];

  f32x4 acc[4][4] = {};
  const int wm = (wid >> 1) * 64, wn = (wid & 1) * 64;

  for (int k0 = 0; k0 < 1024; k0 += 32) {
    gload_lds16(gA + k0,             lA0);
    gload_lds16(gA + k0 + 16 * 1024, lA0 + 16 * 32);
    gload_lds16(gB + k0,             lB0);
    gload_lds16(gB + k0 + 16 * 1024, lB0 + 16 * 32);
    __syncthreads();
    bf16x8 fa[4], fb[4];
#pragma unroll
    for (int i = 0; i < 4; i++) {
      fa[i] = *(const bf16x8*)&lA[(wm + i * 16 + fr) * 32 + fq * 8];
      fb[i] = *(const bf16x8*)&lB[(wn + i * 16 + fr) * 32 + fq * 8];
    }
#pragma unroll
    for (int i = 0; i < 4; i++)
#pragma unroll
      for (int j = 0; j < 4; j++)
        acc[i][j] = __builtin_amdgcn_mfma_f32_16x16x32_bf16(fa[i], fb[j], acc[i][j], 0, 0, 0);
    __syncthreads();
  }

  if (EPI == 1) {
    // fp32 + bias, ldc = 1024
#pragma unroll
    for (int i = 0; i < 4; i++)
#pragma unroll
      for (int j = 0; j < 4; j++)
#pragma unroll
        for (int r = 0; r < 4; r++) {
          int row = bm * 128 + wm + i * 16 + fq * 4 + r;
          int col = bn * 128 + wn + j * 16 + fr;
          ((float*)Cv)[(size_t)row * 1024 + col] = acc[i][j][r] + bias[col];
        }
    return;
  }

  const int col0 = bn * 128;   // wave-uniform region select (128 | 1024)
  if (col0 < 1024) {
    // ---- Q region: row-major bf16 [8192][1024] ----
#pragma unroll
    for (int i = 0; i < 4; i++)
#pragma unroll
      for (int j = 0; j < 4; j++)
#pragma unroll
        for (int r = 0; r < 4; r++) {
          int row = bm * 128 + wm + i * 16 + fq * 4 + r;
          int col = col0 + wn + j * 16 + fr;
          ((u16*)Cv)[(size_t)row * 1024 + col] = f2bf(acc[i][j][r]);
        }
  } else if (col0 < 2048) {
    // ---- K region: fragment-packed KP[((bh*64+jt)*4+sfr)*512 + lane'*8 + e] ----
    // element (s_pos, d of head h): sfr=d>>4, lane'=(s_pos&31)+32*((d>>3)&1), e=d&7
#pragma unroll
    for (int i = 0; i < 4; i++)
#pragma unroll
      for (int j = 0; j < 4; j++) {
        int col = col0 + wn + j * 16 + fr;
        int ck = col - 1024;
        int h = ck >> 6, d = ck & 63;
        int sfr = d >> 4, e = d & 7, hb = (d >> 3) & 1;
#pragma unroll
        for (int r = 0; r < 4; r++) {
          int row = bm * 128 + wm + i * 16 + fq * 4 + r;
          int b = row >> 11, sp = row & 2047;
          int bh = b * 16 + h, jt = sp >> 5;
          int lanep = (sp & 31) + 32 * hb;
          KP[((size_t)(bh * 64 + jt) * 4 + sfr) * 512 + lanep * 8 + e] = f2bf(acc[i][j][r]);
        }
      }
  } else {
    // ---- V region: packed V^T  VP[((bh*64+jt)*4+c)*512 + lane'*8 + e] ----
    // element (s_pos, d): c=(d>>5)*2+((s_pos>>4)&1), lane'=(d&31)+32*((s_pos>>3)&1), e=s_pos&7
#pragma unroll
    for (int i = 0; i < 4; i++)
#pragma unroll
      for (int j = 0; j < 4; j++) {
        int col = col0 + wn + j * 16 + fr;
        int cv = col - 2048;
        int h = cv >> 6, d = cv & 63;
        int R0 = bm * 128 + wm + i * 16 + fq * 4;   // 4-aligned; r=0..3 stays in one e-run
        int b = R0 >> 11, sp0 = R0 & 2047;
        int bh = b * 16 + h, jt = sp0 >> 5;
        int c = (d >> 5) * 2 + ((sp0 >> 4) & 1);
        int lanep = (d & 31) + 32 * ((sp0 >> 3) & 1);
        int e0 = sp0 & 7;
        ushort4 ov;
        ov.x = f2bf(acc[i][j][0]); ov.y = f2bf(acc[i][j][1]);
        ov.z = f2bf(acc[i][j][2]); ov.w = f2bf(acc[i][j][3]);
        *(ushort4*)(VP + ((size_t)(bh * 64 + jt) * 4 + c) * 512 + lanep * 8 + e0) = ov;
      }
  }
}

// ---------------- flash attention (causal), swapped-operand 32x32 MFMA ----------------
// 4 waves/block, wave owns 32 q rows; KV tiles of 32 read from fragment-packed KP/VP.
__global__ __launch_bounds__(256) void attn_kernel(
    const u16* __restrict__ Q, const u16* __restrict__ KP,
    const u16* __restrict__ VP, u16* __restrict__ O) {
  const int tid = threadIdx.x, wid = tid >> 6, lane = tid & 63;
  const int lq = lane & 31, hi = lane >> 5;
  int f = blockIdx.x;
  int xcd = f & 7, kk = f >> 3;
  int bh = xcd * 8 + (kk & 7);
  int qblk = 15 - (kk >> 3);
  int b = bh >> 4, h = bh & 15;
  int q0 = qblk * 128 + wid * 32;
  int q = q0 + lq;

  const u16* Qrow = Q + (size_t)(b * S_LEN + q) * D_DIM + h * HDIM;
  bf16x8 qf[4];
#pragma unroll
  for (int s = 0; s < 4; s++)
    qf[s] = *(const bf16x8*)(Qrow + s * 16 + hi * 8);

  const bf16x8* KPt = (const bf16x8*)KP + (size_t)bh * 64 * 4 * 64;
  const bf16x8* VPt = (const bf16x8*)VP + (size_t)bh * 64 * 4 * 64;

  f32x16 acc0 = {}, acc1 = {};
  float m = -3.0e38f, l = 0.f;
  const int nt = qblk * 4 + wid + 1;

  for (int t = 0; t < nt; ++t) {
    const int j0 = t * 32;
    const size_t fb = (size_t)t * 4 * 64 + lane;
    bf16x8 kf0 = KPt[fb], kf1 = KPt[fb + 64], kf2 = KPt[fb + 128], kf3 = KPt[fb + 192];
    bf16x8 vf00 = VPt[fb], vf01 = VPt[fb + 64], vf10 = VPt[fb + 128], vf11 = VPt[fb + 192];

    f32x16 sa = {};
    __builtin_amdgcn_s_setprio(1);
    sa = __builtin_amdgcn_mfma_f32_32x32x16_bf16(kf0, qf[0], sa, 0, 0, 0);
    sa = __builtin_amdgcn_mfma_f32_32x32x16_bf16(kf1, qf[1], sa, 0, 0, 0);
    sa = __builtin_amdgcn_mfma_f32_32x32x16_bf16(kf2, qf[2], sa, 0, 0, 0);
    sa = __builtin_amdgcn_mfma_f32_32x32x16_bf16(kf3, qf[3], sa, 0, 0, 0);
    __builtin_amdgcn_s_setprio(0);

    float p[16];
#pragma unroll
    for (int r = 0; r < 16; ++r) p[r] = sa[r] * 0.1803368801f;

    if (t == nt - 1) {
#pragma unroll
      for (int r = 0; r < 16; ++r) {
        int kidx = j0 + (r & 3) + 8 * (r >> 2) + 4 * hi;
        if (kidx > q) p[r] = -3.0e38f;
      }
    }

    float x8[8], x4[4], x2[2];
#pragma unroll
    for (int i = 0; i < 8; ++i) x8[i] = fmaxf(p[2 * i], p[2 * i + 1]);
#pragma unroll
    for (int i = 0; i < 4; ++i) x4[i] = fmaxf(x8[2 * i], x8[2 * i + 1]);
    x2[0] = fmaxf(x4[0], x4[1]); x2[1] = fmaxf(x4[2], x4[3]);
    float pm = fmaxf(x2[0], x2[1]);
    pm = fmaxf(pm, __shfl_xor(pm, 32));

    if (__any(pm > m + 11.5f)) {
      float mn = fmaxf(m, pm);
      float sc = EXP2(m - mn);
      l *= sc;
#pragma unroll
      for (int r = 0; r < 16; ++r) { acc0[r] *= sc; acc1[r] *= sc; }
      m = mn;
    }

    float rs = 0.f;
#pragma unroll
    for (int r = 0; r < 16; ++r) { p[r] = EXP2(p[r] - m); rs += p[r]; }
    rs += __shfl_xor(rs, 32);
    l += rs;

    unsigned c0 = cvtpk(p[0],  p[1]),  c1 = cvtpk(p[2],  p[3]);
    unsigned c2 = cvtpk(p[4],  p[5]),  c3 = cvtpk(p[6],  p[7]);
    unsigned c4 = cvtpk(p[8],  p[9]),  c5 = cvtpk(p[10], p[11]);
    unsigned c6 = cvtpk(p[12], p[13]), c7 = cvtpk(p[14], p[15]);
    perm32swap(c0, c2); perm32swap(c1, c3);
    perm32swap(c4, c6); perm32swap(c5, c7);
    union U4 { unsigned u[4]; bf16x8 v; } F0, F1;
    F0.u[0] = c0; F0.u[1] = c1; F0.u[2] = c2; F0.u[3] = c3;
    F1.u[0] = c4; F1.u[1] = c5; F1.u[2] = c6; F1.u[3] = c7;

    __builtin_amdgcn_s_setprio(1);
    acc0 = __builtin_amdgcn_mfma_f32_32x32x16_bf16(vf00, F0.v, acc0, 0, 0, 0);
    acc0 = __builtin_amdgcn_mfma_f32_32x32x16_bf16(vf01, F1.v, acc0, 0, 0, 0);
    acc1 = __builtin_amdgcn_mfma_f32_32x32x16_bf16(vf10, F0.v, acc1, 0, 0, 0);
    acc1 = __builtin_amdgcn_mfma_f32_32x32x16_bf16(vf11, F1.v, acc1, 0, 0, 0);
    __builtin_amdgcn_s_setprio(0);
  }

  float inv = 1.f / l;
  u16* Orow = O + (size_t)(b * S_LEN + q) * D_DIM + h * HDIM;
#pragma unroll
  for (int g = 0; g < 4; ++g) {
    ushort4 o4;
    o4.x = f2bf(acc0[g * 4 + 0] * inv);
    o4.y = f2bf(acc0[g * 4 + 1] * inv);
    o4.z = f2bf(acc0[g * 4 + 2] * inv);
    o4.w = f2bf(acc0[g * 4 + 3] * inv);
    *(ushort4*)(Orow + 8 * g + 4 * hi) = o4;
  }
#pragma unroll
  for (int g = 0; g < 4; ++g) {
    ushort4 o4;
    o4.x = f2bf(acc1[g * 4 + 0] * inv);
    o4.y = f2bf(acc1[g * 4 + 1] * inv);
    o4.z = f2bf(acc1[g * 4 + 2] * inv);
    o4.w = f2bf(acc1[g * 4 + 3] * inv);
    *(ushort4*)(Orow + 32 + 8 * g + 4 * hi) = o4;
  }
}

// ---------------- launcher ----------------
extern "C" void kernel_launch(void* const* d_in, const int* in_sizes, int n_in,
                              void* d_out, int out_size, void* d_ws, size_t ws_size,
                              hipStream_t stream) {
  const float* x  = (const float*)d_in[0];
  const float* wq = (const float*)d_in[1];
  const float* wk = (const float*)d_in[2];
  const float* wv = (const float*)d_in[3];
  const float* wo = (const float*)d_in[4];
  const float* ob = (const float*)d_in[5];
  float* out = (float*)d_out;

  char* ws = (char*)d_ws;
  u16* Xb    = (u16*)(ws);                              // slot A: Xb then Ab
  u16* Ab    = (u16*)(ws);
  u16* Qb    = (u16*)(ws + (size_t)16 * 1024 * 1024);   // 16 MB
  u16* KPb   = (u16*)(ws + (size_t)32 * 1024 * 1024);   // 16 MB
  u16* VPb   = (u16*)(ws + (size_t)48 * 1024 * 1024);   // 16 MB
  u16* WqkvT = (u16*)(ws + (size_t)64 * 1024 * 1024);   // 6 MB
  u16* WoT   = (u16*)(ws + (size_t)70 * 1024 * 1024);   // 2 MB

  cvt_x_kernel<<<(MROWS * D_DIM / 4) / 256, 256, 0, stream>>>(x, Xb, MROWS * D_DIM / 4);

  transpose_w4_kernel<<<dim3(32, 32, 4), dim3(32, 8), 0, stream>>>(
      wq, wk, wv, wo, WqkvT, WoT);

  // fused QKV projection [8192,1024]x[1024,3072] with fused Q/K/V pack epilogue
  gemm_bt_kernel<0><<<dim3(24, 64), 256, 0, stream>>>(
      Xb, WqkvT, Qb, KPb, VPb, nullptr);

  attn_kernel<<<dim3(1024), 256, 0, stream>>>(Qb, KPb, VPb, Ab);

  // out projection [8192,1024]x[1024,1024] + bias, fp32 out
  gemm_bt_kernel<1><<<dim3(8, 64), 256, 0, stream>>>(
      Ab, WoT, out, nullptr, nullptr, ob);
}

// Round 7
// 172.786 us; speedup vs baseline: 1.1365x; 1.0278x over previous
//
#include <hip/hip_runtime.h>
#include <hip/hip_bf16.h>

#define S_LEN 2048
#define D_DIM 1024
#define NHEAD 16
#define HDIM  64
#define BATCH 4
#define MROWS (BATCH*S_LEN)   /* 8192 */

typedef short bf16x8 __attribute__((ext_vector_type(8)));
typedef float f32x4  __attribute__((ext_vector_type(4)));
typedef float f32x16 __attribute__((ext_vector_type(16)));
typedef unsigned short u16;

#if __has_builtin(__builtin_amdgcn_exp2f)
#define EXP2(x) __builtin_amdgcn_exp2f(x)
#else
#define EXP2(x) __expf((x) * 0.6931471805599453f)
#endif

#define BAR() asm volatile("s_barrier" ::: "memory")
#define WAITV0() asm volatile("s_waitcnt vmcnt(0)" ::: "memory")

__device__ inline u16 f2bf(float f) {
  union { float f; unsigned u; } v; v.f = f;
  unsigned r = v.u + 0x7fff + ((v.u >> 16) & 1);   // RNE
  return (u16)(r >> 16);
}

__device__ inline unsigned cvtpk(float lo, float hi_) {
  unsigned d;
  asm("v_cvt_pk_bf16_f32 %0, %1, %2" : "=v"(d) : "v"(lo), "v"(hi_));
  return d;
}

__device__ inline void perm32swap(unsigned& a, unsigned& b) {
  asm volatile("v_permlane32_swap_b32 %0, %1" : "+v"(a), "+v"(b));
}

__device__ inline void gload_lds16(const void* g, void* l) {
  __builtin_amdgcn_global_load_lds(
      (const __attribute__((address_space(1))) void*)g,
      (__attribute__((address_space(3))) void*)l, 16, 0, 0);
}

// ---------------- fp32 -> bf16 convert (vectorized) ----------------
__global__ void cvt_x_kernel(const float* __restrict__ x, u16* __restrict__ xb, int n4) {
  int i = blockIdx.x * 256 + threadIdx.x;
  if (i >= n4) return;
  float4 v = reinterpret_cast<const float4*>(x)[i];
  ushort4 o;
  o.x = f2bf(v.x); o.y = f2bf(v.y); o.z = f2bf(v.z); o.w = f2bf(v.w);
  reinterpret_cast<ushort4*>(xb)[i] = o;
}

// ---------------- all-weights transpose: W[K][N] fp32 -> Wt[N][K] bf16 ----------------
__global__ void transpose_w4_kernel(const float* __restrict__ wq, const float* __restrict__ wk,
                                    const float* __restrict__ wv, const float* __restrict__ wo,
                                    u16* __restrict__ wqkvT, u16* __restrict__ woT) {
  __shared__ float t[32][33];
  int z = blockIdx.z;
  const float* w = (z == 0) ? wq : (z == 1) ? wk : (z == 2) ? wv : wo;
  u16* wt = (z < 3) ? (wqkvT + (size_t)z * 1024 * 1024) : woT;
  int tx = threadIdx.x, ty = threadIdx.y;
  int n0 = blockIdx.x * 32, k0 = blockIdx.y * 32;
#pragma unroll
  for (int j = 0; j < 32; j += 8)
    t[ty + j][tx] = w[(size_t)(k0 + ty + j) * D_DIM + n0 + tx];
  __syncthreads();
#pragma unroll
  for (int j = 0; j < 32; j += 8)
    wt[(size_t)(n0 + ty + j) * D_DIM + k0 + tx] = f2bf(t[tx][ty + j]);
}

// ============ 128x128 bf16 GEMM, dbuf LDS + ONE barrier/K-step, fused epilogues ============
// T3 minimum-2-phase: STAGE(next buf) -> ds_read(cur) -> MFMA -> vmcnt(0) -> s_barrier.
// EPI 0: QKV projection, N=3072. cols 0-1023 -> Qb row-major bf16;
//        cols 1024-2047 -> KP fragment-packed; cols 2048-3071 -> VP packed.
// EPI 1: out projection, N=1024, fp32 C + bias.
template <int EPI>
__global__ __launch_bounds__(256) void gemm_bt_kernel(
    const u16* __restrict__ A, const u16* __restrict__ Bt,
    void* __restrict__ Cv, u16* __restrict__ KP, u16* __restrict__ VP,
    const float* __restrict__ bias) {
  __shared__ u16 lA[2][128 * 32];
  __shared__ u16 lB[2][128 * 32];
  const int tid = threadIdx.x, wid = tid >> 6, lane = tid & 63;
  const int bm = blockIdx.y, bn = blockIdx.x;
  const int fr = lane & 15, fq = lane >> 4;
  const int r0 = wid * 32;
  const int srow = lane >> 2, scol = (lane & 3) * 8;
  const u16* gA = A + (size_t)(bm * 128 + r0 + srow) * 1024 + scol;
  const u16* gB = Bt + (size_t)(bn * 128 + r0 + srow) * 1024 + scol;

  f32x4 acc[4][4] = {};
  const int wm = (wid >> 1) * 64, wn = (wid & 1) * 64;

  // prologue: tile 0 -> buf 0
  gload_lds16(gA,             &lA[0][r0 * 32]);
  gload_lds16(gA + 16 * 1024, &lA[0][r0 * 32 + 16 * 32]);
  gload_lds16(gB,             &lB[0][r0 * 32]);
  gload_lds16(gB + 16 * 1024, &lB[0][r0 * 32 + 16 * 32]);
  WAITV0();
  BAR();

#pragma unroll
  for (int k0 = 0; k0 < 1024; k0 += 32) {
    const int cur = (k0 >> 5) & 1, nxt = cur ^ 1;
    if (k0 + 32 < 1024) {   // stage next tile into the buffer we finished last iter
      gload_lds16(gA + k0 + 32,             &lA[nxt][r0 * 32]);
      gload_lds16(gA + k0 + 32 + 16 * 1024, &lA[nxt][r0 * 32 + 16 * 32]);
      gload_lds16(gB + k0 + 32,             &lB[nxt][r0 * 32]);
      gload_lds16(gB + k0 + 32 + 16 * 1024, &lB[nxt][r0 * 32 + 16 * 32]);
    }
    bf16x8 fa[4], fb[4];
#pragma unroll
    for (int i = 0; i < 4; i++) {
      fa[i] = *(const bf16x8*)&lA[cur][(wm + i * 16 + fr) * 32 + fq * 8];
      fb[i] = *(const bf16x8*)&lB[cur][(wn + i * 16 + fr) * 32 + fq * 8];
    }
#pragma unroll
    for (int i = 0; i < 4; i++)
#pragma unroll
      for (int j = 0; j < 4; j++)
        acc[i][j] = __builtin_amdgcn_mfma_f32_16x16x32_bf16(fa[i], fb[j], acc[i][j], 0, 0, 0);
    WAITV0();   // next tile landed (loads had ds_read+MFMA time to fly)
    BAR();      // one barrier per K-step; ds_reads of [cur] already consumed
  }

  if (EPI == 1) {
    // fp32 + bias, ldc = 1024
#pragma unroll
    for (int i = 0; i < 4; i++)
#pragma unroll
      for (int j = 0; j < 4; j++)
#pragma unroll
        for (int r = 0; r < 4; r++) {
          int row = bm * 128 + wm + i * 16 + fq * 4 + r;
          int col = bn * 128 + wn + j * 16 + fr;
          ((float*)Cv)[(size_t)row * 1024 + col] = acc[i][j][r] + bias[col];
        }
    return;
  }

  const int col0 = bn * 128;   // wave-uniform region select (128 | 1024)
  if (col0 < 1024) {
    // ---- Q region: row-major bf16 [8192][1024] ----
#pragma unroll
    for (int i = 0; i < 4; i++)
#pragma unroll
      for (int j = 0; j < 4; j++)
#pragma unroll
        for (int r = 0; r < 4; r++) {
          int row = bm * 128 + wm + i * 16 + fq * 4 + r;
          int col = col0 + wn + j * 16 + fr;
          ((u16*)Cv)[(size_t)row * 1024 + col] = f2bf(acc[i][j][r]);
        }
  } else if (col0 < 2048) {
    // ---- K region: fragment-packed KP[((bh*64+jt)*4+sfr)*512 + lane'*8 + e] ----
#pragma unroll
    for (int i = 0; i < 4; i++)
#pragma unroll
      for (int j = 0; j < 4; j++) {
        int col = col0 + wn + j * 16 + fr;
        int ck = col - 1024;
        int h = ck >> 6, d = ck & 63;
        int sfr = d >> 4, e = d & 7, hb = (d >> 3) & 1;
#pragma unroll
        for (int r = 0; r < 4; r++) {
          int row = bm * 128 + wm + i * 16 + fq * 4 + r;
          int b = row >> 11, sp = row & 2047;
          int bh = b * 16 + h, jt = sp >> 5;
          int lanep = (sp & 31) + 32 * hb;
          KP[((size_t)(bh * 64 + jt) * 4 + sfr) * 512 + lanep * 8 + e] = f2bf(acc[i][j][r]);
        }
      }
  } else {
    // ---- V region: packed V^T  VP[((bh*64+jt)*4+c)*512 + lane'*8 + e] ----
#pragma unroll
    for (int i = 0; i < 4; i++)
#pragma unroll
      for (int j = 0; j < 4; j++) {
        int col = col0 + wn + j * 16 + fr;
        int cv = col - 2048;
        int h = cv >> 6, d = cv & 63;
        int R0 = bm * 128 + wm + i * 16 + fq * 4;   // 4-aligned; r=0..3 in one e-run
        int b = R0 >> 11, sp0 = R0 & 2047;
        int bh = b * 16 + h, jt = sp0 >> 5;
        int c = (d >> 5) * 2 + ((sp0 >> 4) & 1);
        int lanep = (d & 31) + 32 * ((sp0 >> 3) & 1);
        int e0 = sp0 & 7;
        ushort4 ov;
        ov.x = f2bf(acc[i][j][0]); ov.y = f2bf(acc[i][j][1]);
        ov.z = f2bf(acc[i][j][2]); ov.w = f2bf(acc[i][j][3]);
        *(ushort4*)(VP + ((size_t)(bh * 64 + jt) * 4 + c) * 512 + lanep * 8 + e0) = ov;
      }
  }
}

// ---------------- flash attention (causal), swapped-operand 32x32 MFMA ----------------
__global__ __launch_bounds__(256) void attn_kernel(
    const u16* __restrict__ Q, const u16* __restrict__ KP,
    const u16* __restrict__ VP, u16* __restrict__ O) {
  const int tid = threadIdx.x, wid = tid >> 6, lane = tid & 63;
  const int lq = lane & 31, hi = lane >> 5;
  int f = blockIdx.x;
  int xcd = f & 7, kk = f >> 3;
  int bh = xcd * 8 + (kk & 7);
  int qblk = 15 - (kk >> 3);
  int b = bh >> 4, h = bh & 15;
  int q0 = qblk * 128 + wid * 32;
  int q = q0 + lq;

  const u16* Qrow = Q + (size_t)(b * S_LEN + q) * D_DIM + h * HDIM;
  bf16x8 qf[4];
#pragma unroll
  for (int s = 0; s < 4; s++)
    qf[s] = *(const bf16x8*)(Qrow + s * 16 + hi * 8);

  const bf16x8* KPt = (const bf16x8*)KP + (size_t)bh * 64 * 4 * 64;
  const bf16x8* VPt = (const bf16x8*)VP + (size_t)bh * 64 * 4 * 64;

  f32x16 acc0 = {}, acc1 = {};
  float m = -3.0e38f, l = 0.f;
  const int nt = qblk * 4 + wid + 1;

  for (int t = 0; t < nt; ++t) {
    const int j0 = t * 32;
    const size_t fb = (size_t)t * 4 * 64 + lane;
    bf16x8 kf0 = KPt[fb], kf1 = KPt[fb + 64], kf2 = KPt[fb + 128], kf3 = KPt[fb + 192];
    bf16x8 vf00 = VPt[fb], vf01 = VPt[fb + 64], vf10 = VPt[fb + 128], vf11 = VPt[fb + 192];

    f32x16 sa = {};
    __builtin_amdgcn_s_setprio(1);
    sa = __builtin_amdgcn_mfma_f32_32x32x16_bf16(kf0, qf[0], sa, 0, 0, 0);
    sa = __builtin_amdgcn_mfma_f32_32x32x16_bf16(kf1, qf[1], sa, 0, 0, 0);
    sa = __builtin_amdgcn_mfma_f32_32x32x16_bf16(kf2, qf[2], sa, 0, 0, 0);
    sa = __builtin_amdgcn_mfma_f32_32x32x16_bf16(kf3, qf[3], sa, 0, 0, 0);
    __builtin_amdgcn_s_setprio(0);

    float p[16];
#pragma unroll
    for (int r = 0; r < 16; ++r) p[r] = sa[r] * 0.1803368801f;

    if (t == nt - 1) {
#pragma unroll
      for (int r = 0; r < 16; ++r) {
        int kidx = j0 + (r & 3) + 8 * (r >> 2) + 4 * hi;
        if (kidx > q) p[r] = -3.0e38f;
      }
    }

    float x8[8], x4[4], x2[2];
#pragma unroll
    for (int i = 0; i < 8; ++i) x8[i] = fmaxf(p[2 * i], p[2 * i + 1]);
#pragma unroll
    for (int i = 0; i < 4; ++i) x4[i] = fmaxf(x8[2 * i], x8[2 * i + 1]);
    x2[0] = fmaxf(x4[0], x4[1]); x2[1] = fmaxf(x4[2], x4[3]);
    float pm = fmaxf(x2[0], x2[1]);
    pm = fmaxf(pm, __shfl_xor(pm, 32));

    if (__any(pm > m + 11.5f)) {
      float mn = fmaxf(m, pm);
      float sc = EXP2(m - mn);
      l *= sc;
#pragma unroll
      for (int r = 0; r < 16; ++r) { acc0[r] *= sc; acc1[r] *= sc; }
      m = mn;
    }

    float rs = 0.f;
#pragma unroll
    for (int r = 0; r < 16; ++r) { p[r] = EXP2(p[r] - m); rs += p[r]; }
    rs += __shfl_xor(rs, 32);
    l += rs;

    unsigned c0 = cvtpk(p[0],  p[1]),  c1 = cvtpk(p[2],  p[3]);
    unsigned c2 = cvtpk(p[4],  p[5]),  c3 = cvtpk(p[6],  p[7]);
    unsigned c4 = cvtpk(p[8],  p[9]),  c5 = cvtpk(p[10], p[11]);
    unsigned c6 = cvtpk(p[12], p[13]), c7 = cvtpk(p[14], p[15]);
    perm32swap(c0, c2); perm32swap(c1, c3);
    perm32swap(c4, c6); perm32swap(c5, c7);
    union U4 { unsigned u[4]; bf16x8 v; } F0, F1;
    F0.u[0] = c0; F0.u[1] = c1; F0.u[2] = c2; F0.u[3] = c3;
    F1.u[0] = c4; F1.u[1] = c5; F1.u[2] = c6; F1.u[3] = c7;

    __builtin_amdgcn_s_setprio(1);
    acc0 = __builtin_amdgcn_mfma_f32_32x32x16_bf16(vf00, F0.v, acc0, 0, 0, 0);
    acc0 = __builtin_amdgcn_mfma_f32_32x32x16_bf16(vf01, F1.v, acc0, 0, 0, 0);
    acc1 = __builtin_amdgcn_mfma_f32_32x32x16_bf16(vf10, F0.v, acc1, 0, 0, 0);
    acc1 = __builtin_amdgcn_mfma_f32_32x32x16_bf16(vf11, F1.v, acc1, 0, 0, 0);
    __builtin_amdgcn_s_setprio(0);
  }

  float inv = 1.f / l;
  u16* Orow = O + (size_t)(b * S_LEN + q) * D_DIM + h * HDIM;
#pragma unroll
  for (int g = 0; g < 4; ++g) {
    ushort4 o4;
    o4.x = f2bf(acc0[g * 4 + 0] * inv);
    o4.y = f2bf(acc0[g * 4 + 1] * inv);
    o4.z = f2bf(acc0[g * 4 + 2] * inv);
    o4.w = f2bf(acc0[g * 4 + 3] * inv);
    *(ushort4*)(Orow + 8 * g + 4 * hi) = o4;
  }
#pragma unroll
  for (int g = 0; g < 4; ++g) {
    ushort4 o4;
    o4.x = f2bf(acc1[g * 4 + 0] * inv);
    o4.y = f2bf(acc1[g * 4 + 1] * inv);
    o4.z = f2bf(acc1[g * 4 + 2] * inv);
    o4.w = f2bf(acc1[g * 4 + 3] * inv);
    *(ushort4*)(Orow + 32 + 8 * g + 4 * hi) = o4;
  }
}

// ---------------- launcher ----------------
extern "C" void kernel_launch(void* const* d_in, const int* in_sizes, int n_in,
                              void* d_out, int out_size, void* d_ws, size_t ws_size,
                              hipStream_t stream) {
  const float* x  = (const float*)d_in[0];
  const float* wq = (const float*)d_in[1];
  const float* wk = (const float*)d_in[2];
  const float* wv = (const float*)d_in[3];
  const float* wo = (const float*)d_in[4];
  const float* ob = (const float*)d_in[5];
  float* out = (float*)d_out;

  char* ws = (char*)d_ws;
  u16* Xb    = (u16*)(ws);                              // slot A: Xb then Ab
  u16* Ab    = (u16*)(ws);
  u16* Qb    = (u16*)(ws + (size_t)16 * 1024 * 1024);   // 16 MB
  u16* KPb   = (u16*)(ws + (size_t)32 * 1024 * 1024);   // 16 MB
  u16* VPb   = (u16*)(ws + (size_t)48 * 1024 * 1024);   // 16 MB
  u16* WqkvT = (u16*)(ws + (size_t)64 * 1024 * 1024);   // 6 MB
  u16* WoT   = (u16*)(ws + (size_t)70 * 1024 * 1024);   // 2 MB

  cvt_x_kernel<<<(MROWS * D_DIM / 4) / 256, 256, 0, stream>>>(x, Xb, MROWS * D_DIM / 4);

  transpose_w4_kernel<<<dim3(32, 32, 4), dim3(32, 8), 0, stream>>>(
      wq, wk, wv, wo, WqkvT, WoT);

  // fused QKV projection [8192,1024]x[1024,3072] with fused Q/K/V pack epilogue
  gemm_bt_kernel<0><<<dim3(24, 64), 256, 0, stream>>>(
      Xb, WqkvT, Qb, KPb, VPb, nullptr);

  attn_kernel<<<dim3(1024), 256, 0, stream>>>(Qb, KPb, VPb, Ab);

  // out projection [8192,1024]x[1024,1024] + bias, fp32 out
  gemm_bt_kernel<1><<<dim3(8, 64), 256, 0, stream>>>(
      Ab, WoT, out, nullptr, nullptr, ob);
}